// Round 16
// baseline (1346.709 us; speedup 1.0000x reference)
//
#include <hip/hip_runtime.h>

// Problem constants
#define NB      32      // batch
#define INF     128     // in_flt
#define NPIX    64      // N
#define TSP     16      // t
#define OUTF    32      // out_flt
#define FF      16      // intermediate features
#define D_IN    768     // 3*t*t
#define D_OUT   8192    // out_flt*t*t
#define NCOL    (D_OUT*FF)   // 131072
#define OUTCH   160     // in_flt + out_flt
#define BSTRIDE 655360  // 160*64*64 floats per batch in d_out
#define KCH     4       // k-chunks
#define KROWS   192     // rows per k-chunk
#define NBNCOL  ((size_t)NB*NCOL)

// K1: fused strided conv (128ch,4x4,stride4 -> 3ch) + x->out concat copy.
__global__ __launch_bounds__(256) void k1_conv_copy(
    const float* __restrict__ x, const float* __restrict__ wc,
    float* __restrict__ out, float* __restrict__ At)
{
    __shared__ float sW[3*128*16];     // 24 KB
    __shared__ float sP[16][16][3];
    const int b   = blockIdx.x >> 4;
    const int oi  = blockIdx.x & 15;
    const int tid = threadIdx.x;
    for (int idx = tid; idx < 6144; idx += 256) sW[idx] = wc[idx];
    __syncthreads();
    const int icg = tid >> 4;
    const int j   = tid & 15;
    float a0 = 0.f, a1 = 0.f, a2 = 0.f;
    for (int ic8 = 0; ic8 < 8; ++ic8) {
        const int ic = icg*8 + ic8;
        #pragma unroll
        for (int ki = 0; ki < 4; ++ki) {
            const int row = 4*oi + ki;
            const float4 xv = *(const float4*)(x + ((size_t)(b*INF+ic)*NPIX + row)*NPIX + 4*j);
            *(float4*)(out + ((size_t)(b*OUTCH+ic)*NPIX + row)*NPIX + 4*j) = xv;
            const float* w0 = sW + ((0*INF+ic)*4 + ki)*4;
            const float* w1 = sW + ((1*INF+ic)*4 + ki)*4;
            const float* w2 = sW + ((2*INF+ic)*4 + ki)*4;
            a0 += xv.x*w0[0] + xv.y*w0[1] + xv.z*w0[2] + xv.w*w0[3];
            a1 += xv.x*w1[0] + xv.y*w1[1] + xv.z*w1[2] + xv.w*w1[3];
            a2 += xv.x*w2[0] + xv.y*w2[1] + xv.z*w2[2] + xv.w*w2[3];
        }
    }
    sP[icg][j][0] = a0; sP[icg][j][1] = a1; sP[icg][j][2] = a2;
    __syncthreads();
    if (tid < 48) {
        const int c3 = tid >> 4, jj = tid & 15;
        float s = 0.f;
        #pragma unroll
        for (int g = 0; g < 16; ++g) s += sP[g][jj][c3];
        At[(c3*256 + oi*16 + jj)*32 + b] = s;
    }
}

// ===== R15 A/B/C: three k2 variants, x3 reps each, identical output ======
// v13 base: 256thr, A via uniform s_load, no LDS, depth-4 T-ring, no spill.
// 106us/rep, VALUBusy 42% (= pure fmac time), warm==cold -> ~800cyc/step
// on-chip stall. vA tests "exposed s_load latency" (1-step A prefetch);
// vC tests "vmcnt ring too shallow" (depth 8); vB replicates baseline.

#define FMG(G, AV, T4) { \
  acc[(G)*4+0][0]+=AV.x*T4.x; acc[(G)*4+0][1]+=AV.x*T4.y; acc[(G)*4+0][2]+=AV.x*T4.z; acc[(G)*4+0][3]+=AV.x*T4.w; \
  acc[(G)*4+1][0]+=AV.y*T4.x; acc[(G)*4+1][1]+=AV.y*T4.y; acc[(G)*4+1][2]+=AV.y*T4.z; acc[(G)*4+1][3]+=AV.y*T4.w; \
  acc[(G)*4+2][0]+=AV.z*T4.x; acc[(G)*4+2][1]+=AV.z*T4.y; acc[(G)*4+2][2]+=AV.z*T4.z; acc[(G)*4+2][3]+=AV.z*T4.w; \
  acc[(G)*4+3][0]+=AV.w*T4.x; acc[(G)*4+3][1]+=AV.w*T4.y; acc[(G)*4+3][2]+=AV.w*T4.z; acc[(G)*4+3][3]+=AV.w*T4.w; }
#define K2_PRE \
    const int tid = threadIdx.x; \
    const int kc  = blockIdx.x >> 7; \
    const int cc  = blockIdx.x & 127; \
    const int k0g = kc * KROWS; \
    const float* tp = Tm + (size_t)k0g*NCOL + cc*1024 + tid*4; \
    const float* ap = At + k0g*32;
#define K2_WRITE \
    float* mp = Mp + (size_t)kc*NBNCOL + cc*1024 + tid*4; \
    _Pragma("unroll") \
    for (int bb = 0; bb < 32; ++bb) \
        *(float4*)(mp + (size_t)bb*NCOL) = \
            make_float4(acc[bb][0], acc[bb][1], acc[bb][2], acc[bb][3]);
#define TLD(KK) (*(const float4*)(tp + (size_t)(KK)*NCOL))

// vB: v13 baseline (replication).
__global__ __launch_bounds__(256) void k2_vb(
    const float* __restrict__ At, const float* __restrict__ Tm,
    float* __restrict__ Mp)
{
    K2_PRE
    for (int rep = 0; rep < 3; ++rep) {
        float acc[32][4];
        #pragma unroll
        for (int i = 0; i < 32; ++i)
            #pragma unroll
            for (int j = 0; j < 4; ++j) acc[i][j] = 0.f;
#define ALD(J) \
    const float* ar = ap + (k0+(J))*32; \
    const float4 a0=*(const float4*)(ar+0),  a1=*(const float4*)(ar+4), \
                 a2=*(const float4*)(ar+8),  a3=*(const float4*)(ar+12), \
                 a4=*(const float4*)(ar+16), a5=*(const float4*)(ar+20), \
                 a6=*(const float4*)(ar+24), a7=*(const float4*)(ar+28);
#define STEP(J, RT) { ALD(J) \
    FMG(0,a0,RT) FMG(1,a1,RT) FMG(2,a2,RT) FMG(3,a3,RT) \
    FMG(4,a4,RT) FMG(5,a5,RT) FMG(6,a6,RT) FMG(7,a7,RT) \
    RT = TLD(k0 + 4 + (J)); }
#define STEPE(J, RT) { ALD(J) \
    FMG(0,a0,RT) FMG(1,a1,RT) FMG(2,a2,RT) FMG(3,a3,RT) \
    FMG(4,a4,RT) FMG(5,a5,RT) FMG(6,a6,RT) FMG(7,a7,RT) }
        float4 r0=TLD(0), r1=TLD(1), r2=TLD(2), r3=TLD(3);
        int k0 = 0;
        for (; k0 < KROWS - 4; k0 += 4) { STEP(0,r0) STEP(1,r1) STEP(2,r2) STEP(3,r3) }
        STEPE(0,r0) STEPE(1,r1) STEPE(2,r2) STEPE(3,r3)
#undef STEPE
#undef STEP
#undef ALD
        K2_WRITE
    }
}

// vC: ring depth 8 (tests vmcnt-depth theory).
__global__ __launch_bounds__(256) void k2_vc(
    const float* __restrict__ At, const float* __restrict__ Tm,
    float* __restrict__ Mp)
{
    K2_PRE
    for (int rep = 0; rep < 3; ++rep) {
        float acc[32][4];
        #pragma unroll
        for (int i = 0; i < 32; ++i)
            #pragma unroll
            for (int j = 0; j < 4; ++j) acc[i][j] = 0.f;
#define ALD(J) \
    const float* ar = ap + (k0+(J))*32; \
    const float4 a0=*(const float4*)(ar+0),  a1=*(const float4*)(ar+4), \
                 a2=*(const float4*)(ar+8),  a3=*(const float4*)(ar+12), \
                 a4=*(const float4*)(ar+16), a5=*(const float4*)(ar+20), \
                 a6=*(const float4*)(ar+24), a7=*(const float4*)(ar+28);
#define STEP(J, RT) { ALD(J) \
    FMG(0,a0,RT) FMG(1,a1,RT) FMG(2,a2,RT) FMG(3,a3,RT) \
    FMG(4,a4,RT) FMG(5,a5,RT) FMG(6,a6,RT) FMG(7,a7,RT) \
    RT = TLD(k0 + 8 + (J)); }
#define STEPE(J, RT) { ALD(J) \
    FMG(0,a0,RT) FMG(1,a1,RT) FMG(2,a2,RT) FMG(3,a3,RT) \
    FMG(4,a4,RT) FMG(5,a5,RT) FMG(6,a6,RT) FMG(7,a7,RT) }
        float4 r0=TLD(0), r1=TLD(1), r2=TLD(2), r3=TLD(3),
               r4=TLD(4), r5=TLD(5), r6=TLD(6), r7=TLD(7);
        int k0 = 0;
        for (; k0 < KROWS - 8; k0 += 8) {
            STEP(0,r0) STEP(1,r1) STEP(2,r2) STEP(3,r3)
            STEP(4,r4) STEP(5,r5) STEP(6,r6) STEP(7,r7)
        }
        STEPE(0,r0) STEPE(1,r1) STEPE(2,r2) STEPE(3,r3)
        STEPE(4,r4) STEPE(5,r5) STEPE(6,r6) STEPE(7,r7)
#undef STEPE
#undef STEP
#undef ALD
        K2_WRITE
    }
}

// vA: 1-step A-register prefetch (tests exposed-s_load-latency theory).
// Last prefetch reads row KROWS (128B past At for kc=3) - lands in ws, safe.
__global__ __launch_bounds__(256) void k2_va(
    const float* __restrict__ At, const float* __restrict__ Tm,
    float* __restrict__ Mp)
{
    K2_PRE
    for (int rep = 0; rep < 3; ++rep) {
        float acc[32][4];
        #pragma unroll
        for (int i = 0; i < 32; ++i)
            #pragma unroll
            for (int j = 0; j < 4; ++j) acc[i][j] = 0.f;
#define APRE(KK) \
    const float* nr = ap + (KK)*32; \
    const float4 n0=*(const float4*)(nr+0),  n1=*(const float4*)(nr+4), \
                 n2=*(const float4*)(nr+8),  n3=*(const float4*)(nr+12), \
                 n4=*(const float4*)(nr+16), n5=*(const float4*)(nr+20), \
                 n6=*(const float4*)(nr+24), n7=*(const float4*)(nr+28);
#define STEP(J, RT) { APRE(k0+(J)+1) \
    FMG(0,c0,RT) FMG(1,c1,RT) FMG(2,c2,RT) FMG(3,c3,RT) \
    FMG(4,c4,RT) FMG(5,c5,RT) FMG(6,c6,RT) FMG(7,c7,RT) \
    RT = TLD(k0 + 4 + (J)); \
    c0=n0; c1=n1; c2=n2; c3=n3; c4=n4; c5=n5; c6=n6; c7=n7; }
#define STEPE(J, RT) { APRE(k0+(J)+1) \
    FMG(0,c0,RT) FMG(1,c1,RT) FMG(2,c2,RT) FMG(3,c3,RT) \
    FMG(4,c4,RT) FMG(5,c5,RT) FMG(6,c6,RT) FMG(7,c7,RT) \
    c0=n0; c1=n1; c2=n2; c3=n3; c4=n4; c5=n5; c6=n6; c7=n7; }
        float4 r0=TLD(0), r1=TLD(1), r2=TLD(2), r3=TLD(3);
        float4 c0=*(const float4*)(ap+0),  c1=*(const float4*)(ap+4),
               c2=*(const float4*)(ap+8),  c3=*(const float4*)(ap+12),
               c4=*(const float4*)(ap+16), c5=*(const float4*)(ap+20),
               c6=*(const float4*)(ap+24), c7=*(const float4*)(ap+28);
        int k0 = 0;
        for (; k0 < KROWS - 4; k0 += 4) { STEP(0,r0) STEP(1,r1) STEP(2,r2) STEP(3,r3) }
        STEPE(0,r0) STEPE(1,r1) STEPE(2,r2) STEPE(3,r3)
#undef STEPE
#undef STEP
#undef APRE
        K2_WRITE
    }
}
#undef TLD
#undef K2_WRITE
#undef K2_PRE
#undef FMG

// K3: pairwise L1 + exp; merges 4 k-chunk partials on load.
__global__ __launch_bounds__(256) void k3_pairs(
    const float* __restrict__ Mp, float* __restrict__ outS)
{
    extern __shared__ float sM[];
    const int tid = threadIdx.x;
    const int dd0 = blockIdx.x * 32;
    for (int idx = tid; idx < 32*32*16; idx += 256) {
        const int i = idx >> 9, rem = idx & 511, d = rem >> 4, f = rem & 15;
        const size_t off = (size_t)i*NCOL + (size_t)dd0*16 + rem;
        sM[(i*32 + d)*17 + f] = (Mp[off] + Mp[off + NBNCOL])
                              + (Mp[off + 2*NBNCOL] + Mp[off + 3*NBNCOL]);
    }
    __syncthreads();
    const int j = tid >> 3;
    for (int q = 0; q < 4; ++q) {
        const int d = (tid & 7) + q*8;
        float mj[16];
        const float* pj = sM + (j*32 + d)*17;
        #pragma unroll
        for (int f = 0; f < 16; ++f) mj[f] = pj[f];
        float acc = 0.f;
        for (int i = 0; i < 32; ++i) {
            const float* pi = sM + (i*32 + d)*17;
            float dist = 0.f;
            #pragma unroll
            for (int f = 0; f < 16; ++f) dist += fabsf(pi[f] - mj[f]);
            acc += __expf(-dist);
        }
        outS[(size_t)j*D_OUT + dd0 + d] = acc - 1.0f;
    }
}

// K4: ConvTranspose2d, stride==kernel -> no overlap.
__global__ __launch_bounds__(256) void k4_deconv(
    const float* __restrict__ outS, const float* __restrict__ wd,
    float* __restrict__ out)
{
    __shared__ float sO[32*256];
    __shared__ float sWd[32*16];
    const int b   = blockIdx.x >> 5;
    const int oc  = blockIdx.x & 31;
    const int tid = threadIdx.x;
    for (int idx = tid; idx < 8192; idx += 256) sO[idx] = outS[(size_t)b*D_OUT + idx];
    for (int idx = tid; idx < 512; idx += 256) {
        const int ic = idx >> 4, r = idx & 15;
        sWd[idx] = wd[((ic*32 + oc) << 4) + r];
    }
    __syncthreads();
    float* ob = out + (size_t)b*BSTRIDE + (size_t)(128 + oc)*4096;
    for (int s = 0; s < 16; ++s) {
        const int p  = tid + (s << 8);
        const int i  = p >> 6, jc = p & 63;
        const int si = i >> 2, ki = i & 3, sj = jc >> 2, kj = jc & 3;
        float acc = 0.f;
        #pragma unroll
        for (int ic = 0; ic < 32; ++ic)
            acc += sO[ic*256 + si*16 + sj] * sWd[ic*16 + ki*4 + kj];
        ob[p] = acc;
    }
}

extern "C" void kernel_launch(void* const* d_in, const int* in_sizes, int n_in,
                              void* d_out, int out_size, void* d_ws, size_t ws_size,
                              hipStream_t stream) {
    const float* x  = (const float*)d_in[0];
    const float* wc = (const float*)d_in[1];
    const float* Tm = (const float*)d_in[2];
    const float* wd = (const float*)d_in[3];
    float* out  = (float*)d_out;
    float* At   = (float*)d_ws;                        // 96 KB @ 0
    float* Mp   = (float*)((char*)d_ws + (1 << 20));   // 67 MB @ 1 MB
    float* outS = (float*)((char*)d_ws + (72 << 20));  // 1 MB @ 72 MB

    k1_conv_copy<<<NB*TSP, 256, 0, stream>>>(x, wc, out, At);
    k2_vb<<<KCH*128, 256, 0, stream>>>(At, Tm, Mp);    // baseline, x3
    k2_vc<<<KCH*128, 256, 0, stream>>>(At, Tm, Mp);    // depth-8 ring, x3
    k2_va<<<KCH*128, 256, 0, stream>>>(At, Tm, Mp);    // A-prefetch, x3
    k3_pairs<<<D_OUT/32, 256, 32*32*17*sizeof(float), stream>>>(Mp, outS);
    k4_deconv<<<NB*OUTF, 256, 0, stream>>>(outS, wd, out);
}

// Round 17
// 201.410 us; speedup vs baseline: 6.6864x; 6.6864x over previous
//
#include <hip/hip_runtime.h>

// Problem constants
#define NB      32      // batch
#define INF     128     // in_flt
#define NPIX    64      // N
#define TSP     16      // t
#define OUTF    32      // out_flt
#define FF      16      // intermediate features
#define D_IN    768     // 3*t*t
#define D_OUT   8192    // out_flt*t*t
#define NCOL    (D_OUT*FF)   // 131072
#define OUTCH   160     // in_flt + out_flt
#define BSTRIDE 655360  // 160*64*64 floats per batch in d_out
#define KCH     4       // k-chunks
#define KROWS   192     // rows per k-chunk
#define NBNCOL  ((size_t)NB*NCOL)

// K1: fused strided conv (128ch,4x4,stride4 -> 3ch) + x->out concat copy.
__global__ __launch_bounds__(256) void k1_conv_copy(
    const float* __restrict__ x, const float* __restrict__ wc,
    float* __restrict__ out, float* __restrict__ At)
{
    __shared__ float sW[3*128*16];     // 24 KB
    __shared__ float sP[16][16][3];
    const int b   = blockIdx.x >> 4;
    const int oi  = blockIdx.x & 15;
    const int tid = threadIdx.x;
    for (int idx = tid; idx < 6144; idx += 256) sW[idx] = wc[idx];
    __syncthreads();
    const int icg = tid >> 4;
    const int j   = tid & 15;
    float a0 = 0.f, a1 = 0.f, a2 = 0.f;
    for (int ic8 = 0; ic8 < 8; ++ic8) {
        const int ic = icg*8 + ic8;
        #pragma unroll
        for (int ki = 0; ki < 4; ++ki) {
            const int row = 4*oi + ki;
            const float4 xv = *(const float4*)(x + ((size_t)(b*INF+ic)*NPIX + row)*NPIX + 4*j);
            *(float4*)(out + ((size_t)(b*OUTCH+ic)*NPIX + row)*NPIX + 4*j) = xv;
            const float* w0 = sW + ((0*INF+ic)*4 + ki)*4;
            const float* w1 = sW + ((1*INF+ic)*4 + ki)*4;
            const float* w2 = sW + ((2*INF+ic)*4 + ki)*4;
            a0 += xv.x*w0[0] + xv.y*w0[1] + xv.z*w0[2] + xv.w*w0[3];
            a1 += xv.x*w1[0] + xv.y*w1[1] + xv.z*w1[2] + xv.w*w1[3];
            a2 += xv.x*w2[0] + xv.y*w2[1] + xv.z*w2[2] + xv.w*w2[3];
        }
    }
    sP[icg][j][0] = a0; sP[icg][j][1] = a1; sP[icg][j][2] = a2;
    __syncthreads();
    if (tid < 48) {
        const int c3 = tid >> 4, jj = tid & 15;
        float s = 0.f;
        #pragma unroll
        for (int g = 0; g < 16; ++g) s += sP[g][jj][c3];
        At[(c3*256 + oi*16 + jj)*32 + b] = s;
    }
}

// K2 v15 = v13 + A-prefetch (R16 A/B/C: vA won, 106 -> 97us/rep; vC
// depth-8 ring regressed 2.2x via occupancy loss; vB replicated 106).
// Structure: 256thr, 4 k-chunks x 128 col-chunks, A via uniform s_load
// (SGPR path, lgkmcnt) prefetched ONE k-step ahead (covers ~300-500cyc
// K$-miss latency behind 256 cyc of fmacs), depth-4 named T-ring on a
// pure vmcnt queue, acc[32][4], no LDS, no spill (VGPR ~112-150 < 256).
// Floor: max(HBM 64us, VALU 41us) at 15.3 FLOP/B intensity.
__global__ __launch_bounds__(256) void k2_gemm(
    const float* __restrict__ At, const float* __restrict__ Tm,
    float* __restrict__ Mp)
{
    const int tid = threadIdx.x;
    const int kc  = blockIdx.x >> 7;   // 0..3   (SGPR)
    const int cc  = blockIdx.x & 127;  // 0..127 (SGPR)
    const int k0g = kc * KROWS;

    const float* tp = Tm + (size_t)k0g*NCOL + cc*1024 + tid*4;
    const float* ap = At + k0g*32;     // uniform -> s_load path

    float acc[32][4];
    #pragma unroll
    for (int i = 0; i < 32; ++i)
        #pragma unroll
        for (int j = 0; j < 4; ++j) acc[i][j] = 0.f;

#define TLD(KK) (*(const float4*)(tp + (size_t)(KK)*NCOL))
#define FMG(G, AV, T4) { \
  acc[(G)*4+0][0]+=AV.x*T4.x; acc[(G)*4+0][1]+=AV.x*T4.y; acc[(G)*4+0][2]+=AV.x*T4.z; acc[(G)*4+0][3]+=AV.x*T4.w; \
  acc[(G)*4+1][0]+=AV.y*T4.x; acc[(G)*4+1][1]+=AV.y*T4.y; acc[(G)*4+1][2]+=AV.y*T4.z; acc[(G)*4+1][3]+=AV.y*T4.w; \
  acc[(G)*4+2][0]+=AV.z*T4.x; acc[(G)*4+2][1]+=AV.z*T4.y; acc[(G)*4+2][2]+=AV.z*T4.z; acc[(G)*4+2][3]+=AV.z*T4.w; \
  acc[(G)*4+3][0]+=AV.w*T4.x; acc[(G)*4+3][1]+=AV.w*T4.y; acc[(G)*4+3][2]+=AV.w*T4.z; acc[(G)*4+3][3]+=AV.w*T4.w; }
// Prefetch next k-row of A while consuming the current one (c0..c7).
// Final prefetch reads row KROWS: for kc=3 that's 128B past At, which is
// still inside d_ws (Mp starts at +1MB) - safe dead read.
#define APRE(KK) \
    const float* nr = ap + (KK)*32; \
    const float4 n0=*(const float4*)(nr+0),  n1=*(const float4*)(nr+4), \
                 n2=*(const float4*)(nr+8),  n3=*(const float4*)(nr+12), \
                 n4=*(const float4*)(nr+16), n5=*(const float4*)(nr+20), \
                 n6=*(const float4*)(nr+24), n7=*(const float4*)(nr+28);
#define STEP(J, RT) { APRE(k0+(J)+1) \
    FMG(0,c0,RT) FMG(1,c1,RT) FMG(2,c2,RT) FMG(3,c3,RT) \
    FMG(4,c4,RT) FMG(5,c5,RT) FMG(6,c6,RT) FMG(7,c7,RT) \
    RT = TLD(k0 + 4 + (J)); \
    c0=n0; c1=n1; c2=n2; c3=n3; c4=n4; c5=n5; c6=n6; c7=n7; }
#define STEPE(J, RT) { APRE(k0+(J)+1) \
    FMG(0,c0,RT) FMG(1,c1,RT) FMG(2,c2,RT) FMG(3,c3,RT) \
    FMG(4,c4,RT) FMG(5,c5,RT) FMG(6,c6,RT) FMG(7,c7,RT) \
    c0=n0; c1=n1; c2=n2; c3=n3; c4=n4; c5=n5; c6=n6; c7=n7; }

    float4 r0=TLD(0), r1=TLD(1), r2=TLD(2), r3=TLD(3);
    float4 c0=*(const float4*)(ap+0),  c1=*(const float4*)(ap+4),
           c2=*(const float4*)(ap+8),  c3=*(const float4*)(ap+12),
           c4=*(const float4*)(ap+16), c5=*(const float4*)(ap+20),
           c6=*(const float4*)(ap+24), c7=*(const float4*)(ap+28);

    int k0 = 0;
    for (; k0 < KROWS - 4; k0 += 4) {
        STEP(0, r0) STEP(1, r1) STEP(2, r2) STEP(3, r3)
    }
    // epilogue: k0 == KROWS-4, consume only
    STEPE(0, r0) STEPE(1, r1) STEPE(2, r2) STEPE(3, r3)
#undef STEPE
#undef STEP
#undef APRE
#undef FMG
#undef TLD

    float* mp = Mp + (size_t)kc*NBNCOL + cc*1024 + tid*4;
    #pragma unroll
    for (int bb = 0; bb < 32; ++bb)
        *(float4*)(mp + (size_t)bb*NCOL) =
            make_float4(acc[bb][0], acc[bb][1], acc[bb][2], acc[bb][3]);
}

// K3: out[j,d] = sum_i exp(-sum_f |M[i,d,f]-M[j,d,f]|) - 1.
// Merges the 4 k-chunk partials while loading into LDS.
__global__ __launch_bounds__(256) void k3_pairs(
    const float* __restrict__ Mp, float* __restrict__ outS)
{
    extern __shared__ float sM[];      // 32*32*17 floats
    const int tid = threadIdx.x;
    const int dd0 = blockIdx.x * 32;
    for (int idx = tid; idx < 32*32*16; idx += 256) {
        const int i = idx >> 9, rem = idx & 511, d = rem >> 4, f = rem & 15;
        const size_t off = (size_t)i*NCOL + (size_t)dd0*16 + rem;
        sM[(i*32 + d)*17 + f] = (Mp[off] + Mp[off + NBNCOL])
                              + (Mp[off + 2*NBNCOL] + Mp[off + 3*NBNCOL]);
    }
    __syncthreads();
    const int j = tid >> 3;
    for (int q = 0; q < 4; ++q) {
        const int d = (tid & 7) + q*8;
        float mj[16];
        const float* pj = sM + (j*32 + d)*17;
        #pragma unroll
        for (int f = 0; f < 16; ++f) mj[f] = pj[f];
        float acc = 0.f;
        for (int i = 0; i < 32; ++i) {
            const float* pi = sM + (i*32 + d)*17;
            float dist = 0.f;
            #pragma unroll
            for (int f = 0; f < 16; ++f) dist += fabsf(pi[f] - mj[f]);
            acc += __expf(-dist);
        }
        outS[(size_t)j*D_OUT + dd0 + d] = acc - 1.0f;
    }
}

// K4: ConvTranspose2d, stride==kernel -> no overlap.
__global__ __launch_bounds__(256) void k4_deconv(
    const float* __restrict__ outS, const float* __restrict__ wd,
    float* __restrict__ out)
{
    __shared__ float sO[32*256];
    __shared__ float sWd[32*16];
    const int b   = blockIdx.x >> 5;
    const int oc  = blockIdx.x & 31;
    const int tid = threadIdx.x;
    for (int idx = tid; idx < 8192; idx += 256) sO[idx] = outS[(size_t)b*D_OUT + idx];
    for (int idx = tid; idx < 512; idx += 256) {
        const int ic = idx >> 4, r = idx & 15;
        sWd[idx] = wd[((ic*32 + oc) << 4) + r];
    }
    __syncthreads();
    float* ob = out + (size_t)b*BSTRIDE + (size_t)(128 + oc)*4096;
    for (int s = 0; s < 16; ++s) {
        const int p  = tid + (s << 8);
        const int i  = p >> 6, jc = p & 63;
        const int si = i >> 2, ki = i & 3, sj = jc >> 2, kj = jc & 3;
        float acc = 0.f;
        #pragma unroll
        for (int ic = 0; ic < 32; ++ic)
            acc += sO[ic*256 + si*16 + sj] * sWd[ic*16 + ki*4 + kj];
        ob[p] = acc;
    }
}

extern "C" void kernel_launch(void* const* d_in, const int* in_sizes, int n_in,
                              void* d_out, int out_size, void* d_ws, size_t ws_size,
                              hipStream_t stream) {
    const float* x  = (const float*)d_in[0];
    const float* wc = (const float*)d_in[1];
    const float* Tm = (const float*)d_in[2];
    const float* wd = (const float*)d_in[3];
    float* out  = (float*)d_out;
    float* At   = (float*)d_ws;                        // 96 KB @ 0
    float* Mp   = (float*)((char*)d_ws + (1 << 20));   // 67 MB @ 1 MB
    float* outS = (float*)((char*)d_ws + (72 << 20));  // 1 MB @ 72 MB

    k1_conv_copy<<<NB*TSP, 256, 0, stream>>>(x, wc, out, At);                   // 512 blocks
    k2_gemm    <<<KCH*128, 256, 0, stream>>>(At, Tm, Mp);                       // 512 blocks
    k3_pairs   <<<D_OUT/32, 256, 32*32*17*sizeof(float), stream>>>(Mp, outS);   // 256 blocks
    k4_deconv  <<<NB*OUTF, 256, 0, stream>>>(outS, wd, out);                    // 1024 blocks
}

// Round 18
// 199.119 us; speedup vs baseline: 6.7633x; 1.0115x over previous
//
#include <hip/hip_runtime.h>

// Problem constants
#define NB      32      // batch
#define INF     128     // in_flt
#define NPIX    64      // N
#define TSP     16      // t
#define OUTF    32      // out_flt
#define FF      16      // intermediate features
#define D_IN    768     // 3*t*t
#define D_OUT   8192    // out_flt*t*t
#define NCOL    (D_OUT*FF)   // 131072
#define OUTCH   160     // in_flt + out_flt
#define BSTRIDE 655360  // 160*64*64 floats per batch in d_out
#define KCH     4       // k-chunks
#define KROWS   192     // rows per k-chunk
#define NBNCOL  ((size_t)NB*NCOL)

// K1: fused strided conv (128ch,4x4,stride4 -> 3ch) + x->out concat copy.
__global__ __launch_bounds__(256) void k1_conv_copy(
    const float* __restrict__ x, const float* __restrict__ wc,
    float* __restrict__ out, float* __restrict__ At)
{
    __shared__ float sW[3*128*16];     // 24 KB
    __shared__ float sP[16][16][3];
    const int b   = blockIdx.x >> 4;
    const int oi  = blockIdx.x & 15;
    const int tid = threadIdx.x;
    for (int idx = tid; idx < 6144; idx += 256) sW[idx] = wc[idx];
    __syncthreads();
    const int icg = tid >> 4;
    const int j   = tid & 15;
    float a0 = 0.f, a1 = 0.f, a2 = 0.f;
    for (int ic8 = 0; ic8 < 8; ++ic8) {
        const int ic = icg*8 + ic8;
        #pragma unroll
        for (int ki = 0; ki < 4; ++ki) {
            const int row = 4*oi + ki;
            const float4 xv = *(const float4*)(x + ((size_t)(b*INF+ic)*NPIX + row)*NPIX + 4*j);
            *(float4*)(out + ((size_t)(b*OUTCH+ic)*NPIX + row)*NPIX + 4*j) = xv;
            const float* w0 = sW + ((0*INF+ic)*4 + ki)*4;
            const float* w1 = sW + ((1*INF+ic)*4 + ki)*4;
            const float* w2 = sW + ((2*INF+ic)*4 + ki)*4;
            a0 += xv.x*w0[0] + xv.y*w0[1] + xv.z*w0[2] + xv.w*w0[3];
            a1 += xv.x*w1[0] + xv.y*w1[1] + xv.z*w1[2] + xv.w*w1[3];
            a2 += xv.x*w2[0] + xv.y*w2[1] + xv.z*w2[2] + xv.w*w2[3];
        }
    }
    sP[icg][j][0] = a0; sP[icg][j][1] = a1; sP[icg][j][2] = a2;
    __syncthreads();
    if (tid < 48) {
        const int c3 = tid >> 4, jj = tid & 15;
        float s = 0.f;
        #pragma unroll
        for (int g = 0; g < 16; ++g) s += sP[g][jj][c3];
        At[(c3*256 + oi*16 + jj)*32 + b] = s;
    }
}

// K2 v16: HIGH-TLP (target 6 waves/SIMD). Evidence chain: single-shot k2
// scales with waves/SIMD (2w=152us v15, 4w=126us v14) -> stall-bound, TLP
// is the lever. v16: block 512thr = 4 batch-groups x 128 col-thr (512-col
// range); B_t=8 -> acc[8][4]=32 VGPR + ring 16 + addr ~12 (A is SGPR via
// uniform s_load - proven by v13's VGPR=112 < acc+ring need). Cap 85 via
// launch_bounds(512,6) -> 3 blocks/CU = 24 waves/CU. Grid 4kc x 256cc =
// 1024 blocks. Group T-re-read (4x instrs) is L1-served (2KB/row, same CU);
// TA ~41us || VALU ~41us on separate pipes. Keeps vA A-prefetch (SGPRs,
// free) + depth-4 named T-ring on a pure vmcnt queue.
__global__ __launch_bounds__(512, 6) void k2_gemm(
    const float* __restrict__ At, const float* __restrict__ Tm,
    float* __restrict__ Mp)
{
    const int tid = threadIdx.x;
    const int kc  = blockIdx.x >> 8;   // 0..3   (SGPR)
    const int cc  = blockIdx.x & 255;  // 0..255 (SGPR)
    const int k0g = kc * KROWS;
    const int bg  = __builtin_amdgcn_readfirstlane(tid >> 7);  // 0..3, wave-uniform
    const int ct  = tid & 127;

    const float* tp = Tm + (size_t)k0g*NCOL + cc*512 + ct*4;
    const float* ap = At + k0g*32 + bg*8;    // uniform -> s_load path

    float acc[8][4];
    #pragma unroll
    for (int i = 0; i < 8; ++i)
        #pragma unroll
        for (int j = 0; j < 4; ++j) acc[i][j] = 0.f;

#define TLD(KK) (*(const float4*)(tp + (size_t)(KK)*NCOL))
#define FMG(G, AV, T4) { \
  acc[(G)*4+0][0]+=AV.x*T4.x; acc[(G)*4+0][1]+=AV.x*T4.y; acc[(G)*4+0][2]+=AV.x*T4.z; acc[(G)*4+0][3]+=AV.x*T4.w; \
  acc[(G)*4+1][0]+=AV.y*T4.x; acc[(G)*4+1][1]+=AV.y*T4.y; acc[(G)*4+1][2]+=AV.y*T4.z; acc[(G)*4+1][3]+=AV.y*T4.w; \
  acc[(G)*4+2][0]+=AV.z*T4.x; acc[(G)*4+2][1]+=AV.z*T4.y; acc[(G)*4+2][2]+=AV.z*T4.z; acc[(G)*4+2][3]+=AV.z*T4.w; \
  acc[(G)*4+3][0]+=AV.w*T4.x; acc[(G)*4+3][1]+=AV.w*T4.y; acc[(G)*4+3][2]+=AV.w*T4.z; acc[(G)*4+3][3]+=AV.w*T4.w; }
// A-prefetch one k-row ahead (SGPR path). Final prefetch reads row KROWS:
// for kc=3 that's <1KB past At, still inside d_ws (Mp at +1MB) - safe.
#define APRE(KK) \
    const float* nr = ap + (KK)*32; \
    const float4 n0 = *(const float4*)(nr + 0); \
    const float4 n1 = *(const float4*)(nr + 4);
#define STEP(J, RT) { APRE(k0+(J)+1) \
    FMG(0,c0,RT) FMG(1,c1,RT) \
    RT = TLD(k0 + 4 + (J)); \
    c0 = n0; c1 = n1; }
#define STEPE(J, RT) { APRE(k0+(J)+1) \
    FMG(0,c0,RT) FMG(1,c1,RT) \
    c0 = n0; c1 = n1; }

    float4 r0=TLD(0), r1=TLD(1), r2=TLD(2), r3=TLD(3);
    float4 c0 = *(const float4*)(ap + 0);
    float4 c1 = *(const float4*)(ap + 4);

    int k0 = 0;
    for (; k0 < KROWS - 4; k0 += 4) {
        STEP(0, r0) STEP(1, r1) STEP(2, r2) STEP(3, r3)
    }
    // epilogue: k0 == KROWS-4, consume only
    STEPE(0, r0) STEPE(1, r1) STEPE(2, r2) STEPE(3, r3)
#undef STEPE
#undef STEP
#undef APRE
#undef FMG
#undef TLD

    float* mp = Mp + (size_t)kc*NBNCOL + (size_t)(bg*8)*NCOL + cc*512 + ct*4;
    #pragma unroll
    for (int bb = 0; bb < 8; ++bb)
        *(float4*)(mp + (size_t)bb*NCOL) =
            make_float4(acc[bb][0], acc[bb][1], acc[bb][2], acc[bb][3]);
}

// K3: out[j,d] = sum_i exp(-sum_f |M[i,d,f]-M[j,d,f]|) - 1.
// Merges the 4 k-chunk partials while loading into LDS.
__global__ __launch_bounds__(256) void k3_pairs(
    const float* __restrict__ Mp, float* __restrict__ outS)
{
    extern __shared__ float sM[];      // 32*32*17 floats
    const int tid = threadIdx.x;
    const int dd0 = blockIdx.x * 32;
    for (int idx = tid; idx < 32*32*16; idx += 256) {
        const int i = idx >> 9, rem = idx & 511, d = rem >> 4, f = rem & 15;
        const size_t off = (size_t)i*NCOL + (size_t)dd0*16 + rem;
        sM[(i*32 + d)*17 + f] = (Mp[off] + Mp[off + NBNCOL])
                              + (Mp[off + 2*NBNCOL] + Mp[off + 3*NBNCOL]);
    }
    __syncthreads();
    const int j = tid >> 3;
    for (int q = 0; q < 4; ++q) {
        const int d = (tid & 7) + q*8;
        float mj[16];
        const float* pj = sM + (j*32 + d)*17;
        #pragma unroll
        for (int f = 0; f < 16; ++f) mj[f] = pj[f];
        float acc = 0.f;
        for (int i = 0; i < 32; ++i) {
            const float* pi = sM + (i*32 + d)*17;
            float dist = 0.f;
            #pragma unroll
            for (int f = 0; f < 16; ++f) dist += fabsf(pi[f] - mj[f]);
            acc += __expf(-dist);
        }
        outS[(size_t)j*D_OUT + dd0 + d] = acc - 1.0f;
    }
}

// K4: ConvTranspose2d, stride==kernel -> no overlap.
__global__ __launch_bounds__(256) void k4_deconv(
    const float* __restrict__ outS, const float* __restrict__ wd,
    float* __restrict__ out)
{
    __shared__ float sO[32*256];
    __shared__ float sWd[32*16];
    const int b   = blockIdx.x >> 5;
    const int oc  = blockIdx.x & 31;
    const int tid = threadIdx.x;
    for (int idx = tid; idx < 8192; idx += 256) sO[idx] = outS[(size_t)b*D_OUT + idx];
    for (int idx = tid; idx < 512; idx += 256) {
        const int ic = idx >> 4, r = idx & 15;
        sWd[idx] = wd[((ic*32 + oc) << 4) + r];
    }
    __syncthreads();
    float* ob = out + (size_t)b*BSTRIDE + (size_t)(128 + oc)*4096;
    for (int s = 0; s < 16; ++s) {
        const int p  = tid + (s << 8);
        const int i  = p >> 6, jc = p & 63;
        const int si = i >> 2, ki = i & 3, sj = jc >> 2, kj = jc & 3;
        float acc = 0.f;
        #pragma unroll
        for (int ic = 0; ic < 32; ++ic)
            acc += sO[ic*256 + si*16 + sj] * sWd[ic*16 + ki*4 + kj];
        ob[p] = acc;
    }
}

extern "C" void kernel_launch(void* const* d_in, const int* in_sizes, int n_in,
                              void* d_out, int out_size, void* d_ws, size_t ws_size,
                              hipStream_t stream) {
    const float* x  = (const float*)d_in[0];
    const float* wc = (const float*)d_in[1];
    const float* Tm = (const float*)d_in[2];
    const float* wd = (const float*)d_in[3];
    float* out  = (float*)d_out;
    float* At   = (float*)d_ws;                        // 96 KB @ 0
    float* Mp   = (float*)((char*)d_ws + (1 << 20));   // 67 MB @ 1 MB
    float* outS = (float*)((char*)d_ws + (72 << 20));  // 1 MB @ 72 MB

    k1_conv_copy<<<NB*TSP, 256, 0, stream>>>(x, wc, out, At);                   // 512 blocks
    k2_gemm    <<<KCH*256, 512, 0, stream>>>(At, Tm, Mp);                       // 1024 blocks
    k3_pairs   <<<D_OUT/32, 256, 32*32*17*sizeof(float), stream>>>(Mp, outS);   // 256 blocks
    k4_deconv  <<<NB*OUTF, 256, 0, stream>>>(outS, wd, out);                    // 1024 blocks
}

// Round 19
// 185.480 us; speedup vs baseline: 7.2607x; 1.0735x over previous
//
#include <hip/hip_runtime.h>

// Problem constants
#define NB      32      // batch
#define INF     128     // in_flt
#define NPIX    64      // N
#define TSP     16      // t
#define OUTF    32      // out_flt
#define FF      16      // intermediate features
#define D_IN    768     // 3*t*t
#define D_OUT   8192    // out_flt*t*t
#define NCOL    (D_OUT*FF)   // 131072
#define OUTCH   160     // in_flt + out_flt
#define BSTRIDE 655360  // 160*64*64 floats per batch in d_out
#define KCH     4       // k-chunks
#define KROWS   192     // rows per k-chunk
#define NBNCOL  ((size_t)NB*NCOL)

// K1: fused strided conv (128ch,4x4,stride4 -> 3ch) + x->out concat copy.
__global__ __launch_bounds__(256) void k1_conv_copy(
    const float* __restrict__ x, const float* __restrict__ wc,
    float* __restrict__ out, float* __restrict__ At)
{
    __shared__ float sW[3*128*16];     // 24 KB
    __shared__ float sP[16][16][3];
    const int b   = blockIdx.x >> 4;
    const int oi  = blockIdx.x & 15;
    const int tid = threadIdx.x;
    for (int idx = tid; idx < 6144; idx += 256) sW[idx] = wc[idx];
    __syncthreads();
    const int icg = tid >> 4;
    const int j   = tid & 15;
    float a0 = 0.f, a1 = 0.f, a2 = 0.f;
    for (int ic8 = 0; ic8 < 8; ++ic8) {
        const int ic = icg*8 + ic8;
        #pragma unroll
        for (int ki = 0; ki < 4; ++ki) {
            const int row = 4*oi + ki;
            const float4 xv = *(const float4*)(x + ((size_t)(b*INF+ic)*NPIX + row)*NPIX + 4*j);
            *(float4*)(out + ((size_t)(b*OUTCH+ic)*NPIX + row)*NPIX + 4*j) = xv;
            const float* w0 = sW + ((0*INF+ic)*4 + ki)*4;
            const float* w1 = sW + ((1*INF+ic)*4 + ki)*4;
            const float* w2 = sW + ((2*INF+ic)*4 + ki)*4;
            a0 += xv.x*w0[0] + xv.y*w0[1] + xv.z*w0[2] + xv.w*w0[3];
            a1 += xv.x*w1[0] + xv.y*w1[1] + xv.z*w1[2] + xv.w*w1[3];
            a2 += xv.x*w2[0] + xv.y*w2[1] + xv.z*w2[2] + xv.w*w2[3];
        }
    }
    sP[icg][j][0] = a0; sP[icg][j][1] = a1; sP[icg][j][2] = a2;
    __syncthreads();
    if (tid < 48) {
        const int c3 = tid >> 4, jj = tid & 15;
        float s = 0.f;
        #pragma unroll
        for (int g = 0; g < 16; ++g) s += sP[g][jj][c3];
        At[(c3*256 + oi*16 + jj)*32 + b] = s;
    }
}

// K2 v17: LDS-STAGED T, double-buffered (canonical §5 pattern, reg-staged).
// Ledger closed the register-resident tradeoff: B_t=32/R1/2w=152,
// B_t=16/R2/4w=126 (best), B_t=8/R4/6w=150 -> acc_VGPR x redundancy is a
// hard product. v17 decouples them: T goes HBM->LDS ONCE per block
// (R_global=1); the 4 bg-waves re-read from LDS (69 TB/s pipe, ~12cyc
// ds_read_b128); acc[8][4]=32 VGPR -> ~64-75 total -> 3-4 blocks/CU =
// 6-8 waves/SIMD. Per tile (8 k-rows x 512 cols, 16 KB, 2 buffers):
// issue next tile's 2 global float4/thread -> consume 8 rows (ds_read +
// 32 fmacs) -> vmcnt-wait + ds_write next tile -> barrier (T14 split:
// HBM latency hides under the 8x512cyc consume phase). A via uniform
// s_load per row (TLP covers its latency at 6-8 w/SIMD).
__global__ __launch_bounds__(512, 6) void k2_gemm(
    const float* __restrict__ At, const float* __restrict__ Tm,
    float* __restrict__ Mp)
{
    __shared__ float sT[2][8*512];     // 32 KB double buffer
    const int tid  = threadIdx.x;
    const int kc   = blockIdx.x >> 8;  // 0..3   (SGPR)
    const int cc   = blockIdx.x & 255; // 0..255 (SGPR)
    const int k0g  = kc * KROWS;
    const int bg   = __builtin_amdgcn_readfirstlane(tid >> 7); // 0..3 wave-uniform
    const int ct   = tid & 127;        // col-thread within 512-col range
    const int srow = tid >> 7;         // 0..3 staging row base

    const float* tbase = Tm + (size_t)k0g*NCOL + cc*512;
    const float* ap    = At + k0g*32 + bg*8;   // uniform -> s_load path

    float acc[8][4];
    #pragma unroll
    for (int i = 0; i < 8; ++i)
        #pragma unroll
        for (int j = 0; j < 4; ++j) acc[i][j] = 0.f;

    // prologue: stage tile 0 (rows 0..7)
    {
        const float4 p0 = *(const float4*)(tbase + (size_t)srow*NCOL + ct*4);
        const float4 p1 = *(const float4*)(tbase + (size_t)(srow + 4)*NCOL + ct*4);
        *(float4*)&sT[0][srow*512 + ct*4]     = p0;
        *(float4*)&sT[0][(srow+4)*512 + ct*4] = p1;
    }
    __syncthreads();

    for (int t = 0; t < KROWS/8; ++t) {
        const int cur = t & 1, nxt = cur ^ 1;
        const bool more = (t + 1 < KROWS/8);
        float4 g0, g1;
        if (more) {     // issue next tile's global loads EARLY (T14 split)
            const float* gs = tbase + (size_t)((t+1)*8 + srow)*NCOL + ct*4;
            g0 = *(const float4*)(gs);
            g1 = *(const float4*)(gs + (size_t)4*NCOL);
        }
        // consume tile t: 8 k-rows
        #pragma unroll
        for (int r = 0; r < 8; ++r) {
            const float4 tv = *(const float4*)&sT[cur][r*512 + ct*4];
            const float* av = ap + (t*8 + r)*32;   // uniform (SGPR) addr
            const float4 aL = *(const float4*)(av);
            const float4 aH = *(const float4*)(av + 4);
            const float a8[8] = {aL.x,aL.y,aL.z,aL.w, aH.x,aH.y,aH.z,aH.w};
            const float t4[4] = {tv.x,tv.y,tv.z,tv.w};
            #pragma unroll
            for (int i = 0; i < 8; ++i)
                #pragma unroll
                for (int j = 0; j < 4; ++j)
                    acc[i][j] += a8[i]*t4[j];
        }
        if (more) {     // write next tile (vmcnt wait covered by consume)
            *(float4*)&sT[nxt][srow*512 + ct*4]     = g0;
            *(float4*)&sT[nxt][(srow+4)*512 + ct*4] = g1;
        }
        __syncthreads();
    }

    float* mp = Mp + (size_t)kc*NBNCOL + (size_t)(bg*8)*NCOL + cc*512 + ct*4;
    #pragma unroll
    for (int bb = 0; bb < 8; ++bb)
        *(float4*)(mp + (size_t)bb*NCOL) =
            make_float4(acc[bb][0], acc[bb][1], acc[bb][2], acc[bb][3]);
}

// K3: out[j,d] = sum_i exp(-sum_f |M[i,d,f]-M[j,d,f]|) - 1.
// Merges the 4 k-chunk partials while loading into LDS.
__global__ __launch_bounds__(256) void k3_pairs(
    const float* __restrict__ Mp, float* __restrict__ outS)
{
    extern __shared__ float sM[];      // 32*32*17 floats
    const int tid = threadIdx.x;
    const int dd0 = blockIdx.x * 32;
    for (int idx = tid; idx < 32*32*16; idx += 256) {
        const int i = idx >> 9, rem = idx & 511, d = rem >> 4, f = rem & 15;
        const size_t off = (size_t)i*NCOL + (size_t)dd0*16 + rem;
        sM[(i*32 + d)*17 + f] = (Mp[off] + Mp[off + NBNCOL])
                              + (Mp[off + 2*NBNCOL] + Mp[off + 3*NBNCOL]);
    }
    __syncthreads();
    const int j = tid >> 3;
    for (int q = 0; q < 4; ++q) {
        const int d = (tid & 7) + q*8;
        float mj[16];
        const float* pj = sM + (j*32 + d)*17;
        #pragma unroll
        for (int f = 0; f < 16; ++f) mj[f] = pj[f];
        float acc = 0.f;
        for (int i = 0; i < 32; ++i) {
            const float* pi = sM + (i*32 + d)*17;
            float dist = 0.f;
            #pragma unroll
            for (int f = 0; f < 16; ++f) dist += fabsf(pi[f] - mj[f]);
            acc += __expf(-dist);
        }
        outS[(size_t)j*D_OUT + dd0 + d] = acc - 1.0f;
    }
}

// K4: ConvTranspose2d, stride==kernel -> no overlap.
__global__ __launch_bounds__(256) void k4_deconv(
    const float* __restrict__ outS, const float* __restrict__ wd,
    float* __restrict__ out)
{
    __shared__ float sO[32*256];
    __shared__ float sWd[32*16];
    const int b   = blockIdx.x >> 5;
    const int oc  = blockIdx.x & 31;
    const int tid = threadIdx.x;
    for (int idx = tid; idx < 8192; idx += 256) sO[idx] = outS[(size_t)b*D_OUT + idx];
    for (int idx = tid; idx < 512; idx += 256) {
        const int ic = idx >> 4, r = idx & 15;
        sWd[idx] = wd[((ic*32 + oc) << 4) + r];
    }
    __syncthreads();
    float* ob = out + (size_t)b*BSTRIDE + (size_t)(128 + oc)*4096;
    for (int s = 0; s < 16; ++s) {
        const int p  = tid + (s << 8);
        const int i  = p >> 6, jc = p & 63;
        const int si = i >> 2, ki = i & 3, sj = jc >> 2, kj = jc & 3;
        float acc = 0.f;
        #pragma unroll
        for (int ic = 0; ic < 32; ++ic)
            acc += sO[ic*256 + si*16 + sj] * sWd[ic*16 + ki*4 + kj];
        ob[p] = acc;
    }
}

extern "C" void kernel_launch(void* const* d_in, const int* in_sizes, int n_in,
                              void* d_out, int out_size, void* d_ws, size_t ws_size,
                              hipStream_t stream) {
    const float* x  = (const float*)d_in[0];
    const float* wc = (const float*)d_in[1];
    const float* Tm = (const float*)d_in[2];
    const float* wd = (const float*)d_in[3];
    float* out  = (float*)d_out;
    float* At   = (float*)d_ws;                        // 96 KB @ 0
    float* Mp   = (float*)((char*)d_ws + (1 << 20));   // 67 MB @ 1 MB
    float* outS = (float*)((char*)d_ws + (72 << 20));  // 1 MB @ 72 MB

    k1_conv_copy<<<NB*TSP, 256, 0, stream>>>(x, wc, out, At);                   // 512 blocks
    k2_gemm    <<<KCH*256, 512, 0, stream>>>(At, Tm, Mp);                       // 1024 blocks
    k3_pairs   <<<D_OUT/32, 256, 32*32*17*sizeof(float), stream>>>(Mp, outS);   // 256 blocks
    k4_deconv  <<<NB*OUTF, 256, 0, stream>>>(outS, wd, out);                    // 1024 blocks
}

// Round 20
// 177.867 us; speedup vs baseline: 7.5714x; 1.0428x over previous
//
#include <hip/hip_runtime.h>

// Problem constants
#define NB      32      // batch
#define INF     128     // in_flt
#define NPIX    64      // N
#define TSP     16      // t
#define OUTF    32      // out_flt
#define FF      16      // intermediate features
#define D_IN    768     // 3*t*t
#define D_OUT   8192    // out_flt*t*t
#define NCOL    (D_OUT*FF)   // 131072
#define OUTCH   160     // in_flt + out_flt
#define BSTRIDE 655360  // 160*64*64 floats per batch in d_out
#define KCH     4       // k-chunks
#define KROWS   192     // rows per k-chunk
#define NBNCOL  ((size_t)NB*NCOL)

// K1: fused strided conv (128ch,4x4,stride4 -> 3ch) + x->out concat copy.
__global__ __launch_bounds__(256) void k1_conv_copy(
    const float* __restrict__ x, const float* __restrict__ wc,
    float* __restrict__ out, float* __restrict__ At)
{
    __shared__ float sW[3*128*16];     // 24 KB
    __shared__ float sP[16][16][3];
    const int b   = blockIdx.x >> 4;
    const int oi  = blockIdx.x & 15;
    const int tid = threadIdx.x;
    for (int idx = tid; idx < 6144; idx += 256) sW[idx] = wc[idx];
    __syncthreads();
    const int icg = tid >> 4;
    const int j   = tid & 15;
    float a0 = 0.f, a1 = 0.f, a2 = 0.f;
    for (int ic8 = 0; ic8 < 8; ++ic8) {
        const int ic = icg*8 + ic8;
        #pragma unroll
        for (int ki = 0; ki < 4; ++ki) {
            const int row = 4*oi + ki;
            const float4 xv = *(const float4*)(x + ((size_t)(b*INF+ic)*NPIX + row)*NPIX + 4*j);
            *(float4*)(out + ((size_t)(b*OUTCH+ic)*NPIX + row)*NPIX + 4*j) = xv;
            const float* w0 = sW + ((0*INF+ic)*4 + ki)*4;
            const float* w1 = sW + ((1*INF+ic)*4 + ki)*4;
            const float* w2 = sW + ((2*INF+ic)*4 + ki)*4;
            a0 += xv.x*w0[0] + xv.y*w0[1] + xv.z*w0[2] + xv.w*w0[3];
            a1 += xv.x*w1[0] + xv.y*w1[1] + xv.z*w1[2] + xv.w*w1[3];
            a2 += xv.x*w2[0] + xv.y*w2[1] + xv.z*w2[2] + xv.w*w2[3];
        }
    }
    sP[icg][j][0] = a0; sP[icg][j][1] = a1; sP[icg][j][2] = a2;
    __syncthreads();
    if (tid < 48) {
        const int c3 = tid >> 4, jj = tid & 15;
        float s = 0.f;
        #pragma unroll
        for (int g = 0; g < 16; ++g) s += sP[g][jj][c3];
        At[(c3*256 + oi*16 + jj)*32 + b] = s;
    }
}

// K2 v18 = v14 (best single-shot: B_t=16, 2 blocks/CU, 4 w/SIMD,
// in-block redundancy-2 L1-served) + vA's A-register-prefetch (the one
// within-probe-proven delta: 106->97/rep amplified; mechanism = hide the
// ~300-500cyc s_load K$-miss behind the 64 fmacs + 1 T-load of the
// current step). Ledger that selected v14: v13 R1/2w=152, v14 R2/4w=126,
// v16 R4/6w=150, v17 LDS-dbuf=136 -> redundancy x VGPR tradeoff optimum.
// VGPR: acc 64 + ring 16 + A-cur 16 + A-next 16 + addr ~10 = ~122 < 128
// cap of launch_bounds(512,4) -> no spill, occupancy unchanged.
__global__ __launch_bounds__(512, 4) void k2_gemm(
    const float* __restrict__ At, const float* __restrict__ Tm,
    float* __restrict__ Mp)
{
    const int tid = threadIdx.x;
    const int kc  = blockIdx.x >> 7;   // 0..3   (SGPR)
    const int cc  = blockIdx.x & 127;  // 0..127 (SGPR)
    const int k0g = kc * KROWS;
    const int bh  = __builtin_amdgcn_readfirstlane(tid >> 8);  // batch half
    const int ct  = tid & 255;                                 // col-thread

    const float* tp = Tm + (size_t)k0g*NCOL + cc*1024 + ct*4;
    const float* ap = At + k0g*32 + bh*16;   // uniform -> s_load path

    float acc[16][4];
    #pragma unroll
    for (int i = 0; i < 16; ++i)
        #pragma unroll
        for (int j = 0; j < 4; ++j) acc[i][j] = 0.f;

#define TLD(KK) (*(const float4*)(tp + (size_t)(KK)*NCOL))
#define FMG(G, AV, T4) { \
  acc[(G)*4+0][0]+=AV.x*T4.x; acc[(G)*4+0][1]+=AV.x*T4.y; acc[(G)*4+0][2]+=AV.x*T4.z; acc[(G)*4+0][3]+=AV.x*T4.w; \
  acc[(G)*4+1][0]+=AV.y*T4.x; acc[(G)*4+1][1]+=AV.y*T4.y; acc[(G)*4+1][2]+=AV.y*T4.z; acc[(G)*4+1][3]+=AV.y*T4.w; \
  acc[(G)*4+2][0]+=AV.z*T4.x; acc[(G)*4+2][1]+=AV.z*T4.y; acc[(G)*4+2][2]+=AV.z*T4.z; acc[(G)*4+2][3]+=AV.z*T4.w; \
  acc[(G)*4+3][0]+=AV.w*T4.x; acc[(G)*4+3][1]+=AV.w*T4.y; acc[(G)*4+3][2]+=AV.w*T4.z; acc[(G)*4+3][3]+=AV.w*T4.w; }
// A-prefetch one k-row ahead (scalar path). Final prefetch reads row
// KROWS: for kc=3 that's <1KB past At, still ws padding (Mp at +1MB).
#define APRE(KK) \
    const float* nr = ap + (KK)*32; \
    const float4 n0 = *(const float4*)(nr + 0); \
    const float4 n1 = *(const float4*)(nr + 4); \
    const float4 n2 = *(const float4*)(nr + 8); \
    const float4 n3 = *(const float4*)(nr + 12);
#define STEP(J, RT) { APRE(k0+(J)+1) \
    FMG(0,c0,RT) FMG(1,c1,RT) FMG(2,c2,RT) FMG(3,c3,RT) \
    RT = TLD(k0 + 4 + (J)); \
    c0 = n0; c1 = n1; c2 = n2; c3 = n3; }
#define STEPE(J, RT) { APRE(k0+(J)+1) \
    FMG(0,c0,RT) FMG(1,c1,RT) FMG(2,c2,RT) FMG(3,c3,RT) \
    c0 = n0; c1 = n1; c2 = n2; c3 = n3; }

    float4 r0=TLD(0), r1=TLD(1), r2=TLD(2), r3=TLD(3);
    float4 c0 = *(const float4*)(ap + 0);
    float4 c1 = *(const float4*)(ap + 4);
    float4 c2 = *(const float4*)(ap + 8);
    float4 c3 = *(const float4*)(ap + 12);

    int k0 = 0;
    for (; k0 < KROWS - 4; k0 += 4) {
        STEP(0, r0) STEP(1, r1) STEP(2, r2) STEP(3, r3)
    }
    // epilogue: k0 == KROWS-4, consume only
    STEPE(0, r0) STEPE(1, r1) STEPE(2, r2) STEPE(3, r3)
#undef STEPE
#undef STEP
#undef APRE
#undef FMG
#undef TLD

    float* mp = Mp + (size_t)kc*NBNCOL + (size_t)(bh*16)*NCOL + cc*1024 + ct*4;
    #pragma unroll
    for (int bb = 0; bb < 16; ++bb)
        *(float4*)(mp + (size_t)bb*NCOL) =
            make_float4(acc[bb][0], acc[bb][1], acc[bb][2], acc[bb][3]);
}

// K3: out[j,d] = sum_i exp(-sum_f |M[i,d,f]-M[j,d,f]|) - 1.
// Merges the 4 k-chunk partials while loading into LDS.
__global__ __launch_bounds__(256) void k3_pairs(
    const float* __restrict__ Mp, float* __restrict__ outS)
{
    extern __shared__ float sM[];      // 32*32*17 floats
    const int tid = threadIdx.x;
    const int dd0 = blockIdx.x * 32;
    for (int idx = tid; idx < 32*32*16; idx += 256) {
        const int i = idx >> 9, rem = idx & 511, d = rem >> 4, f = rem & 15;
        const size_t off = (size_t)i*NCOL + (size_t)dd0*16 + rem;
        sM[(i*32 + d)*17 + f] = (Mp[off] + Mp[off + NBNCOL])
                              + (Mp[off + 2*NBNCOL] + Mp[off + 3*NBNCOL]);
    }
    __syncthreads();
    const int j = tid >> 3;
    for (int q = 0; q < 4; ++q) {
        const int d = (tid & 7) + q*8;
        float mj[16];
        const float* pj = sM + (j*32 + d)*17;
        #pragma unroll
        for (int f = 0; f < 16; ++f) mj[f] = pj[f];
        float acc = 0.f;
        for (int i = 0; i < 32; ++i) {
            const float* pi = sM + (i*32 + d)*17;
            float dist = 0.f;
            #pragma unroll
            for (int f = 0; f < 16; ++f) dist += fabsf(pi[f] - mj[f]);
            acc += __expf(-dist);
        }
        outS[(size_t)j*D_OUT + dd0 + d] = acc - 1.0f;
    }
}

// K4: ConvTranspose2d, stride==kernel -> no overlap.
__global__ __launch_bounds__(256) void k4_deconv(
    const float* __restrict__ outS, const float* __restrict__ wd,
    float* __restrict__ out)
{
    __shared__ float sO[32*256];
    __shared__ float sWd[32*16];
    const int b   = blockIdx.x >> 5;
    const int oc  = blockIdx.x & 31;
    const int tid = threadIdx.x;
    for (int idx = tid; idx < 8192; idx += 256) sO[idx] = outS[(size_t)b*D_OUT + idx];
    for (int idx = tid; idx < 512; idx += 256) {
        const int ic = idx >> 4, r = idx & 15;
        sWd[idx] = wd[((ic*32 + oc) << 4) + r];
    }
    __syncthreads();
    float* ob = out + (size_t)b*BSTRIDE + (size_t)(128 + oc)*4096;
    for (int s = 0; s < 16; ++s) {
        const int p  = tid + (s << 8);
        const int i  = p >> 6, jc = p & 63;
        const int si = i >> 2, ki = i & 3, sj = jc >> 2, kj = jc & 3;
        float acc = 0.f;
        #pragma unroll
        for (int ic = 0; ic < 32; ++ic)
            acc += sO[ic*256 + si*16 + sj] * sWd[ic*16 + ki*4 + kj];
        ob[p] = acc;
    }
}

extern "C" void kernel_launch(void* const* d_in, const int* in_sizes, int n_in,
                              void* d_out, int out_size, void* d_ws, size_t ws_size,
                              hipStream_t stream) {
    const float* x  = (const float*)d_in[0];
    const float* wc = (const float*)d_in[1];
    const float* Tm = (const float*)d_in[2];
    const float* wd = (const float*)d_in[3];
    float* out  = (float*)d_out;
    float* At   = (float*)d_ws;                        // 96 KB @ 0
    float* Mp   = (float*)((char*)d_ws + (1 << 20));   // 67 MB @ 1 MB
    float* outS = (float*)((char*)d_ws + (72 << 20));  // 1 MB @ 72 MB

    k1_conv_copy<<<NB*TSP, 256, 0, stream>>>(x, wc, out, At);                   // 512 blocks
    k2_gemm    <<<KCH*128, 512, 0, stream>>>(At, Tm, Mp);                       // 512 blocks x 512 thr
    k3_pairs   <<<D_OUT/32, 256, 32*32*17*sizeof(float), stream>>>(Mp, outS);   // 256 blocks
    k4_deconv  <<<NB*OUTF, 256, 0, stream>>>(outS, wd, out);                    // 1024 blocks
}

// Round 21
// 175.343 us; speedup vs baseline: 7.6804x; 1.0144x over previous
//
#include <hip/hip_runtime.h>

// ============================================================================
// FINAL (R20): exact R15/v14 champion configuration, 174.9 us measured.
// k2 ledger (nine structures): v13 R1/2w=152, v14 R2/4w=126 (BEST),
// v16 R4/6w=150, v17 LDS-dbuf=136, v18 v14+Apre=129. Aggregate HBM floor
// ~115-125us (690 MB @ 6.3TB/s); k2's residual ~50us stall survived eight
// targeted mechanisms (spill fix R13 was the one structural win: 230->175).
// ============================================================================

// Problem constants
#define NB      32      // batch
#define INF     128     // in_flt
#define NPIX    64      // N
#define TSP     16      // t
#define OUTF    32      // out_flt
#define FF      16      // intermediate features
#define D_IN    768     // 3*t*t
#define D_OUT   8192    // out_flt*t*t
#define NCOL    (D_OUT*FF)   // 131072
#define OUTCH   160     // in_flt + out_flt
#define BSTRIDE 655360  // 160*64*64 floats per batch in d_out
#define KCH     4       // k-chunks
#define KROWS   192     // rows per k-chunk
#define NBNCOL  ((size_t)NB*NCOL)

// K1: fused strided conv (128ch,4x4,stride4 -> 3ch) + x->out concat copy.
__global__ __launch_bounds__(256) void k1_conv_copy(
    const float* __restrict__ x, const float* __restrict__ wc,
    float* __restrict__ out, float* __restrict__ At)
{
    __shared__ float sW[3*128*16];     // 24 KB
    __shared__ float sP[16][16][3];
    const int b   = blockIdx.x >> 4;
    const int oi  = blockIdx.x & 15;
    const int tid = threadIdx.x;
    for (int idx = tid; idx < 6144; idx += 256) sW[idx] = wc[idx];
    __syncthreads();
    const int icg = tid >> 4;
    const int j   = tid & 15;
    float a0 = 0.f, a1 = 0.f, a2 = 0.f;
    for (int ic8 = 0; ic8 < 8; ++ic8) {
        const int ic = icg*8 + ic8;
        #pragma unroll
        for (int ki = 0; ki < 4; ++ki) {
            const int row = 4*oi + ki;
            const float4 xv = *(const float4*)(x + ((size_t)(b*INF+ic)*NPIX + row)*NPIX + 4*j);
            *(float4*)(out + ((size_t)(b*OUTCH+ic)*NPIX + row)*NPIX + 4*j) = xv;
            const float* w0 = sW + ((0*INF+ic)*4 + ki)*4;
            const float* w1 = sW + ((1*INF+ic)*4 + ki)*4;
            const float* w2 = sW + ((2*INF+ic)*4 + ki)*4;
            a0 += xv.x*w0[0] + xv.y*w0[1] + xv.z*w0[2] + xv.w*w0[3];
            a1 += xv.x*w1[0] + xv.y*w1[1] + xv.z*w1[2] + xv.w*w1[3];
            a2 += xv.x*w2[0] + xv.y*w2[1] + xv.z*w2[2] + xv.w*w2[3];
        }
    }
    sP[icg][j][0] = a0; sP[icg][j][1] = a1; sP[icg][j][2] = a2;
    __syncthreads();
    if (tid < 48) {
        const int c3 = tid >> 4, jj = tid & 15;
        float s = 0.f;
        #pragma unroll
        for (int g = 0; g < 16; ++g) s += sP[g][jj][c3];
        At[(c3*256 + oi*16 + jj)*32 + b] = s;
    }
}

// K2 v14 (champion): block=512thr = 2 batch-halves x 256 col-thr, 1024
// cols/block; grid 4kc x 128cc = 512 blocks -> 2 blocks/CU = 4 waves/SIMD.
// B_t=16 -> acc[16][4]=64 VGPR, no spill under launch_bounds(512,4).
// A via wave-uniform s_load (scalar K$/L2 path, lgkmcnt - disjoint from
// the T vmcnt queue); in-block redundancy-2 T re-read is L1-served.
// Depth-4 named-register T-ring; TLP covers s_load + ring latency.
__global__ __launch_bounds__(512, 4) void k2_gemm(
    const float* __restrict__ At, const float* __restrict__ Tm,
    float* __restrict__ Mp)
{
    const int tid = threadIdx.x;
    const int kc  = blockIdx.x >> 7;   // 0..3   (SGPR)
    const int cc  = blockIdx.x & 127;  // 0..127 (SGPR)
    const int k0g = kc * KROWS;
    const int bh  = __builtin_amdgcn_readfirstlane(tid >> 8);  // batch half
    const int ct  = tid & 255;                                 // col-thread

    const float* tp = Tm + (size_t)k0g*NCOL + cc*1024 + ct*4;
    const float* ap = At + k0g*32 + bh*16;   // uniform -> s_load path

    float acc[16][4];
    #pragma unroll
    for (int i = 0; i < 16; ++i)
        #pragma unroll
        for (int j = 0; j < 4; ++j) acc[i][j] = 0.f;

#define TLD(KK) (*(const float4*)(tp + (size_t)(KK)*NCOL))
#define FMG(G, AV, T4) { \
  acc[(G)*4+0][0]+=AV.x*T4.x; acc[(G)*4+0][1]+=AV.x*T4.y; acc[(G)*4+0][2]+=AV.x*T4.z; acc[(G)*4+0][3]+=AV.x*T4.w; \
  acc[(G)*4+1][0]+=AV.y*T4.x; acc[(G)*4+1][1]+=AV.y*T4.y; acc[(G)*4+1][2]+=AV.y*T4.z; acc[(G)*4+1][3]+=AV.y*T4.w; \
  acc[(G)*4+2][0]+=AV.z*T4.x; acc[(G)*4+2][1]+=AV.z*T4.y; acc[(G)*4+2][2]+=AV.z*T4.z; acc[(G)*4+2][3]+=AV.z*T4.w; \
  acc[(G)*4+3][0]+=AV.w*T4.x; acc[(G)*4+3][1]+=AV.w*T4.y; acc[(G)*4+3][2]+=AV.w*T4.z; acc[(G)*4+3][3]+=AV.w*T4.w; }
#define ALD(J) \
    const float* ar = ap + (k0+(J))*32;          /* uniform (SGPR) addr */ \
    const float4 a0 = *(const float4*)(ar +  0); \
    const float4 a1 = *(const float4*)(ar +  4); \
    const float4 a2 = *(const float4*)(ar +  8); \
    const float4 a3 = *(const float4*)(ar + 12);
#define STEP(J, RT) { ALD(J) \
    FMG(0,a0,RT) FMG(1,a1,RT) FMG(2,a2,RT) FMG(3,a3,RT) \
    RT = TLD(k0 + 4 + (J)); }
#define STEPE(J, RT) { ALD(J) \
    FMG(0,a0,RT) FMG(1,a1,RT) FMG(2,a2,RT) FMG(3,a3,RT) }

    float4 r0=TLD(0), r1=TLD(1), r2=TLD(2), r3=TLD(3);
    int k0 = 0;
    for (; k0 < KROWS - 4; k0 += 4) {
        STEP(0, r0) STEP(1, r1) STEP(2, r2) STEP(3, r3)
    }
    // epilogue: k0 == KROWS-4, consume only
    STEPE(0, r0) STEPE(1, r1) STEPE(2, r2) STEPE(3, r3)
#undef STEPE
#undef STEP
#undef ALD
#undef FMG
#undef TLD

    float* mp = Mp + (size_t)kc*NBNCOL + (size_t)(bh*16)*NCOL + cc*1024 + ct*4;
    #pragma unroll
    for (int bb = 0; bb < 16; ++bb)
        *(float4*)(mp + (size_t)bb*NCOL) =
            make_float4(acc[bb][0], acc[bb][1], acc[bb][2], acc[bb][3]);
}

// K3: out[j,d] = sum_i exp(-sum_f |M[i,d,f]-M[j,d,f]|) - 1.
// Merges the 4 k-chunk partials while loading into LDS.
__global__ __launch_bounds__(256) void k3_pairs(
    const float* __restrict__ Mp, float* __restrict__ outS)
{
    extern __shared__ float sM[];      // 32*32*17 floats
    const int tid = threadIdx.x;
    const int dd0 = blockIdx.x * 32;
    for (int idx = tid; idx < 32*32*16; idx += 256) {
        const int i = idx >> 9, rem = idx & 511, d = rem >> 4, f = rem & 15;
        const size_t off = (size_t)i*NCOL + (size_t)dd0*16 + rem;
        sM[(i*32 + d)*17 + f] = (Mp[off] + Mp[off + NBNCOL])
                              + (Mp[off + 2*NBNCOL] + Mp[off + 3*NBNCOL]);
    }
    __syncthreads();
    const int j = tid >> 3;
    for (int q = 0; q < 4; ++q) {
        const int d = (tid & 7) + q*8;
        float mj[16];
        const float* pj = sM + (j*32 + d)*17;
        #pragma unroll
        for (int f = 0; f < 16; ++f) mj[f] = pj[f];
        float acc = 0.f;
        for (int i = 0; i < 32; ++i) {
            const float* pi = sM + (i*32 + d)*17;
            float dist = 0.f;
            #pragma unroll
            for (int f = 0; f < 16; ++f) dist += fabsf(pi[f] - mj[f]);
            acc += __expf(-dist);
        }
        outS[(size_t)j*D_OUT + dd0 + d] = acc - 1.0f;
    }
}

// K4: ConvTranspose2d, stride==kernel -> no overlap.
__global__ __launch_bounds__(256) void k4_deconv(
    const float* __restrict__ outS, const float* __restrict__ wd,
    float* __restrict__ out)
{
    __shared__ float sO[32*256];
    __shared__ float sWd[32*16];
    const int b   = blockIdx.x >> 5;
    const int oc  = blockIdx.x & 31;
    const int tid = threadIdx.x;
    for (int idx = tid; idx < 8192; idx += 256) sO[idx] = outS[(size_t)b*D_OUT + idx];
    for (int idx = tid; idx < 512; idx += 256) {
        const int ic = idx >> 4, r = idx & 15;
        sWd[idx] = wd[((ic*32 + oc) << 4) + r];
    }
    __syncthreads();
    float* ob = out + (size_t)b*BSTRIDE + (size_t)(128 + oc)*4096;
    for (int s = 0; s < 16; ++s) {
        const int p  = tid + (s << 8);
        const int i  = p >> 6, jc = p & 63;
        const int si = i >> 2, ki = i & 3, sj = jc >> 2, kj = jc & 3;
        float acc = 0.f;
        #pragma unroll
        for (int ic = 0; ic < 32; ++ic)
            acc += sO[ic*256 + si*16 + sj] * sWd[ic*16 + ki*4 + kj];
        ob[p] = acc;
    }
}

extern "C" void kernel_launch(void* const* d_in, const int* in_sizes, int n_in,
                              void* d_out, int out_size, void* d_ws, size_t ws_size,
                              hipStream_t stream) {
    const float* x  = (const float*)d_in[0];
    const float* wc = (const float*)d_in[1];
    const float* Tm = (const float*)d_in[2];
    const float* wd = (const float*)d_in[3];
    float* out  = (float*)d_out;
    float* At   = (float*)d_ws;                        // 96 KB @ 0
    float* Mp   = (float*)((char*)d_ws + (1 << 20));   // 67 MB @ 1 MB
    float* outS = (float*)((char*)d_ws + (72 << 20));  // 1 MB @ 72 MB

    k1_conv_copy<<<NB*TSP, 256, 0, stream>>>(x, wc, out, At);                   // 512 blocks
    k2_gemm    <<<KCH*128, 512, 0, stream>>>(At, Tm, Mp);                       // 512 blocks x 512 thr
    k3_pairs   <<<D_OUT/32, 256, 32*32*17*sizeof(float), stream>>>(Mp, outS);   // 256 blocks
    k4_deconv  <<<NB*OUTF, 256, 0, stream>>>(outS, wd, out);                    // 1024 blocks
}